// Round 4
// baseline (334.380 us; speedup 1.0000x reference)
//
#include <hip/hip_runtime.h>

// HashEmbedding: out[t,:] = [ sum_h W[ht[word,h],:] * P[word,h]  (64 floats),
//                             P[ht[word,0],0], P[ht[word,1],1] ]
// TOKENS=819200, EMBED=64, H=2, out row = 66 floats (264 B).
//
// R2' design (resubmit x3; rounds 0-3 all hit GPU-acquisition timeouts —
// this source has never executed):
// 16 lanes per token-group, 4 groups/wave, 4-token unroll per group
// => 16 tokens/wave (2x R1's MLP). Each lane covers W-row floats
// {2gl,2gl+1} and {32+2gl,32+2gl+1} via two f2 loads, so every W load and
// every embed store is a 128B-contiguous-per-group f2 access (same proven
// coalescing shape as R1). Level-0/1 loads (words/ht/P) serve 4 tokens per
// instruction (4 consecutive addresses across groups), cutting VMEM
// instructions/token 4.5 -> 3.0. Nontemporal stores keep the 216 MB output
// stream out of the L2 that the W/ht/P gathers need.
// pvals gathers live inside the gl==0 branch so only 1 lane per group
// issues them (guaranteed; not left to compiler sinking).

#define TOKENS (16384 * 50)
#define EMBED 64
#define OUT_STRIDE 66
#define TOK_PER_WAVE 16
#define TOK_PER_BLOCK 64  // 4 waves * 16

typedef float f2 __attribute__((ext_vector_type(2)));
typedef int   i2 __attribute__((ext_vector_type(2)));

__global__ __launch_bounds__(256, 4) void HashEmbedding_32401233281223_kernel(
    const int*   __restrict__ words, // [TOKENS]
    const int*   __restrict__ ht,    // [NUM_WORDS,2]
    const float* __restrict__ W,     // [NUM_BUCKETS,64]
    const float* __restrict__ P,     // [NUM_WORDS,2] (also indexed by bucket for pvals)
    float*       __restrict__ out)   // [TOKENS,66]
{
    const int tid  = blockIdx.x * 256 + threadIdx.x;
    const int wave = tid >> 6;
    const int lane = threadIdx.x & 63;
    const int grp  = lane >> 4;   // four 16-lane token-groups per wave
    const int gl   = lane & 15;   // lane within group

    // token for unroll step u: wave*16 + 4u + grp  -> at fixed u the four
    // groups hold 4 CONSECUTIVE tokens (one cache line of word ids, and
    // adjacent 264B output rows).
    const int tb = wave * TOK_PER_WAVE + grp;

    // ---- Level 0: word ids (1 instr / 4 tokens; 4 consecutive addrs) ----
    const int w0 = words[tb + 0];
    const int w1 = words[tb + 4];
    const int w2 = words[tb + 8];
    const int w3 = words[tb + 12];

    // ---- Level 1: hash pairs + per-word P pairs (independent gathers) ----
    const i2* ht2 = (const i2*)ht;
    const f2* P2  = (const f2*)P;
    const i2 h0 = ht2[w0];
    const i2 h1 = ht2[w1];
    const i2 h2 = ht2[w2];
    const i2 h3 = ht2[w3];
    const f2 p0 = P2[w0];
    const f2 p1 = P2[w1];
    const f2 p2 = P2[w2];
    const f2 p3 = P2[w3];

    // ---- Level 2: W rows. Per token 2 rows; lane gl covers floats
    // {2gl,2gl+1} (lo half) and {32+2gl,32+2gl+1} (hi half). 16 independent
    // f2 gathers, each 128B-contiguous per group, 512B per instruction. ----
    const f2* W2 = (const f2*)W;  // row r = W2[r*32 + ...]
    const size_t r0a = (size_t)h0.x * 32, r0b = (size_t)h0.y * 32;
    const size_t r1a = (size_t)h1.x * 32, r1b = (size_t)h1.y * 32;
    const size_t r2a = (size_t)h2.x * 32, r2b = (size_t)h2.y * 32;
    const size_t r3a = (size_t)h3.x * 32, r3b = (size_t)h3.y * 32;
    const f2 al0 = W2[r0a + gl],      ah0 = W2[r0a + 16 + gl];
    const f2 bl0 = W2[r0b + gl],      bh0 = W2[r0b + 16 + gl];
    const f2 al1 = W2[r1a + gl],      ah1 = W2[r1a + 16 + gl];
    const f2 bl1 = W2[r1b + gl],      bh1 = W2[r1b + 16 + gl];
    const f2 al2 = W2[r2a + gl],      ah2 = W2[r2a + 16 + gl];
    const f2 bl2 = W2[r2b + gl],      bh2 = W2[r2b + 16 + gl];
    const f2 al3 = W2[r3a + gl],      ah3 = W2[r3a + 16 + gl];
    const f2 bl3 = W2[r3b + gl],      bh3 = W2[r3b + 16 + gl];

    // ---- Compute ----
    const f2 el0 = al0 * p0.x + bl0 * p0.y, eh0 = ah0 * p0.x + bh0 * p0.y;
    const f2 el1 = al1 * p1.x + bl1 * p1.y, eh1 = ah1 * p1.x + bh1 * p1.y;
    const f2 el2 = al2 * p2.x + bl2 * p2.y, eh2 = ah2 * p2.x + bh2 * p2.y;
    const f2 el3 = al3 * p3.x + bl3 * p3.y, eh3 = ah3 * p3.x + bh3 * p3.y;

    // ---- Stores (nontemporal: output is write-once, keep it out of L2).
    // Row base = 264*t bytes -> 8-aligned for every t, f2 legal. Each store
    // instr: 4 groups x 16 lanes x 8B = 128B contiguous per group. ----
    float* o0 = out + (size_t)(tb + 0)  * OUT_STRIDE;
    float* o1 = out + (size_t)(tb + 4)  * OUT_STRIDE;
    float* o2 = out + (size_t)(tb + 8)  * OUT_STRIDE;
    float* o3 = out + (size_t)(tb + 12) * OUT_STRIDE;
    __builtin_nontemporal_store(el0, (f2*)o0 + gl);
    __builtin_nontemporal_store(eh0, (f2*)o0 + 16 + gl);
    __builtin_nontemporal_store(el1, (f2*)o1 + gl);
    __builtin_nontemporal_store(eh1, (f2*)o1 + 16 + gl);
    __builtin_nontemporal_store(el2, (f2*)o2 + gl);
    __builtin_nontemporal_store(eh2, (f2*)o2 + 16 + gl);
    __builtin_nontemporal_store(el3, (f2*)o3 + gl);
    __builtin_nontemporal_store(eh3, (f2*)o3 + 16 + gl);

    if (gl == 0) {  // one lane per group issues the pvals gathers + stores
        // pvals: P indexed by BUCKET id, column = hash index (800KB, L2-resident)
        const f2 q0 = { P[2 * h0.x + 0], P[2 * h0.y + 1] };
        const f2 q1 = { P[2 * h1.x + 0], P[2 * h1.y + 1] };
        const f2 q2 = { P[2 * h2.x + 0], P[2 * h2.y + 1] };
        const f2 q3 = { P[2 * h3.x + 0], P[2 * h3.y + 1] };
        __builtin_nontemporal_store(q0, (f2*)(o0 + EMBED));
        __builtin_nontemporal_store(q1, (f2*)(o1 + EMBED));
        __builtin_nontemporal_store(q2, (f2*)(o2 + EMBED));
        __builtin_nontemporal_store(q3, (f2*)(o3 + EMBED));
    }
}

extern "C" void kernel_launch(void* const* d_in, const int* in_sizes, int n_in,
                              void* d_out, int out_size, void* d_ws, size_t ws_size,
                              hipStream_t stream) {
    const int*   words      = (const int*)d_in[0];
    const int*   hash_table = (const int*)d_in[1];
    const float* W          = (const float*)d_in[2];
    const float* P          = (const float*)d_in[3];
    float*       out        = (float*)d_out;

    const int blocks = TOKENS / TOK_PER_BLOCK;  // 12800
    HashEmbedding_32401233281223_kernel<<<blocks, 256, 0, stream>>>(
        words, hash_table, W, P, out);
}

// Round 5
// 334.256 us; speedup vs baseline: 1.0004x; 1.0004x over previous
//
#include <hip/hip_runtime.h>

// HashEmbedding: out[t,:] = [ sum_h W[ht[word,h],:] * P[word,h]  (64 floats),
//                             P[ht[word,0],0], P[ht[word,1],1] ]
// TOKENS=819200, EMBED=64, H=2, out row = 66 floats (264 B).
//
// R3 = R2' with ONE change: temporal (normal) stores instead of
// __builtin_nontemporal_store.
// R4 counter evidence: FETCH_SIZE=310MB vs ~45MB of input tables, and
// WRITE_SIZE=258MB vs 216MB output. Theory: nt stores bypass L2
// write-combining, so 8B f2 stores become partial-sector writes that force
// read-modify-write at the memory side -> FETCH absorbs ~216MB of output
// reads + write amplification. Plain stores let each 16-lane group's 128B
// contiguous run merge into full dirty lines in L2; eviction writes clean
// 64B sectors with no RMW fetch.
//
// Structure (unchanged, verified passing @143us kernel / 4.0 TB/s):
// 16 lanes per token-group, 4 groups/wave, 4-token unroll per group
// => 16 tokens/wave. Each lane covers W-row floats {2gl,2gl+1} and
// {32+2gl,32+2gl+1} via two f2 loads: every W load and embed store is a
// 128B-contiguous-per-group access. Level-0/1 loads serve 4 tokens per
// instruction. pvals gathers live inside the gl==0 branch.

#define TOKENS (16384 * 50)
#define EMBED 64
#define OUT_STRIDE 66
#define TOK_PER_WAVE 16
#define TOK_PER_BLOCK 64  // 4 waves * 16

typedef float f2 __attribute__((ext_vector_type(2)));
typedef int   i2 __attribute__((ext_vector_type(2)));

__global__ __launch_bounds__(256, 4) void HashEmbedding_32401233281223_kernel(
    const int*   __restrict__ words, // [TOKENS]
    const int*   __restrict__ ht,    // [NUM_WORDS,2]
    const float* __restrict__ W,     // [NUM_BUCKETS,64]
    const float* __restrict__ P,     // [NUM_WORDS,2] (also indexed by bucket for pvals)
    float*       __restrict__ out)   // [TOKENS,66]
{
    const int tid  = blockIdx.x * 256 + threadIdx.x;
    const int wave = tid >> 6;
    const int lane = threadIdx.x & 63;
    const int grp  = lane >> 4;   // four 16-lane token-groups per wave
    const int gl   = lane & 15;   // lane within group

    // token for unroll step u: wave*16 + 4u + grp  -> at fixed u the four
    // groups hold 4 CONSECUTIVE tokens (one cache line of word ids, and
    // adjacent 264B output rows).
    const int tb = wave * TOK_PER_WAVE + grp;

    // ---- Level 0: word ids (1 instr / 4 tokens; 4 consecutive addrs) ----
    const int w0 = words[tb + 0];
    const int w1 = words[tb + 4];
    const int w2 = words[tb + 8];
    const int w3 = words[tb + 12];

    // ---- Level 1: hash pairs + per-word P pairs (independent gathers) ----
    const i2* ht2 = (const i2*)ht;
    const f2* P2  = (const f2*)P;
    const i2 h0 = ht2[w0];
    const i2 h1 = ht2[w1];
    const i2 h2 = ht2[w2];
    const i2 h3 = ht2[w3];
    const f2 p0 = P2[w0];
    const f2 p1 = P2[w1];
    const f2 p2 = P2[w2];
    const f2 p3 = P2[w3];

    // ---- Level 2: W rows. Per token 2 rows; lane gl covers floats
    // {2gl,2gl+1} (lo half) and {32+2gl,32+2gl+1} (hi half). 16 independent
    // f2 gathers, each 128B-contiguous per group, 512B per instruction. ----
    const f2* W2 = (const f2*)W;  // row r = W2[r*32 + ...]
    const size_t r0a = (size_t)h0.x * 32, r0b = (size_t)h0.y * 32;
    const size_t r1a = (size_t)h1.x * 32, r1b = (size_t)h1.y * 32;
    const size_t r2a = (size_t)h2.x * 32, r2b = (size_t)h2.y * 32;
    const size_t r3a = (size_t)h3.x * 32, r3b = (size_t)h3.y * 32;
    const f2 al0 = W2[r0a + gl],      ah0 = W2[r0a + 16 + gl];
    const f2 bl0 = W2[r0b + gl],      bh0 = W2[r0b + 16 + gl];
    const f2 al1 = W2[r1a + gl],      ah1 = W2[r1a + 16 + gl];
    const f2 bl1 = W2[r1b + gl],      bh1 = W2[r1b + 16 + gl];
    const f2 al2 = W2[r2a + gl],      ah2 = W2[r2a + 16 + gl];
    const f2 bl2 = W2[r2b + gl],      bh2 = W2[r2b + 16 + gl];
    const f2 al3 = W2[r3a + gl],      ah3 = W2[r3a + 16 + gl];
    const f2 bl3 = W2[r3b + gl],      bh3 = W2[r3b + 16 + gl];

    // ---- Compute ----
    const f2 el0 = al0 * p0.x + bl0 * p0.y, eh0 = ah0 * p0.x + bh0 * p0.y;
    const f2 el1 = al1 * p1.x + bl1 * p1.y, eh1 = ah1 * p1.x + bh1 * p1.y;
    const f2 el2 = al2 * p2.x + bl2 * p2.y, eh2 = ah2 * p2.x + bh2 * p2.y;
    const f2 el3 = al3 * p3.x + bl3 * p3.y, eh3 = ah3 * p3.x + bh3 * p3.y;

    // ---- Stores (TEMPORAL: go through L2 so adjacent 8B runs write-combine
    // into full 64B dirty lines; nt stores caused ~216MB of RMW fetch).
    // Row base = 264*t bytes -> 8-aligned for every t, f2 legal. Each store
    // instr: 4 groups x 16 lanes x 8B = 128B contiguous per group. ----
    float* o0 = out + (size_t)(tb + 0)  * OUT_STRIDE;
    float* o1 = out + (size_t)(tb + 4)  * OUT_STRIDE;
    float* o2 = out + (size_t)(tb + 8)  * OUT_STRIDE;
    float* o3 = out + (size_t)(tb + 12) * OUT_STRIDE;
    *((f2*)o0 + gl)      = el0;
    *((f2*)o0 + 16 + gl) = eh0;
    *((f2*)o1 + gl)      = el1;
    *((f2*)o1 + 16 + gl) = eh1;
    *((f2*)o2 + gl)      = el2;
    *((f2*)o2 + 16 + gl) = eh2;
    *((f2*)o3 + gl)      = el3;
    *((f2*)o3 + 16 + gl) = eh3;

    if (gl == 0) {  // one lane per group issues the pvals gathers + stores
        // pvals: P indexed by BUCKET id, column = hash index (800KB, L2-resident)
        const f2 q0 = { P[2 * h0.x + 0], P[2 * h0.y + 1] };
        const f2 q1 = { P[2 * h1.x + 0], P[2 * h1.y + 1] };
        const f2 q2 = { P[2 * h2.x + 0], P[2 * h2.y + 1] };
        const f2 q3 = { P[2 * h3.x + 0], P[2 * h3.y + 1] };
        *((f2*)(o0 + EMBED)) = q0;
        *((f2*)(o1 + EMBED)) = q1;
        *((f2*)(o2 + EMBED)) = q2;
        *((f2*)(o3 + EMBED)) = q3;
    }
}

extern "C" void kernel_launch(void* const* d_in, const int* in_sizes, int n_in,
                              void* d_out, int out_size, void* d_ws, size_t ws_size,
                              hipStream_t stream) {
    const int*   words      = (const int*)d_in[0];
    const int*   hash_table = (const int*)d_in[1];
    const float* W          = (const float*)d_in[2];
    const float* P          = (const float*)d_in[3];
    float*       out        = (float*)d_out;

    const int blocks = TOKENS / TOK_PER_BLOCK;  // 12800
    HashEmbedding_32401233281223_kernel<<<blocks, 256, 0, stream>>>(
        words, hash_table, W, P, out);
}